// Round 2
// baseline (588.115 us; speedup 1.0000x reference)
//
#include <hip/hip_runtime.h>
#include <math.h>

#define HASH_SIZE_LOG2 19
#define HASH_MASK ((1u << HASH_SIZE_LOG2) - 1u)
#define HS (1u << HASH_SIZE_LOG2)
#define NUM_LEVELS 16

struct ResArr { float r[NUM_LEVELS]; };

// Level-pair-partitioned layout:
//   flat bid = chunk*8 + lp  ->  XCD(bid) = bid % 8 = lp  (round-robin dispatch)
// so XCD `lp` only ever gathers from level tables (2lp, 2lp+1): its 4 MB L2
// caches at most 8 MB of table instead of the full 64 MB -> far fewer misses.
// Block = 256 threads = 256 points, one level-pair each; thread writes one
// float4 at out[n*32 + lp*4] (16B of a 64B line; Infinity Cache merges the
// 4 fragments written by 4 different XCDs).
__global__ __launch_bounds__(256) void HashEncoder_67963562492047_kernel(
    const float* __restrict__ x,      // [N,3] f32
    const float* __restrict__ emb,    // [16][HS][2] f32
    float* __restrict__ out,          // [N,32] f32
    ResArr res, int n_points)
{
    __shared__ float sx[256 * 3];

    const int bid = blockIdx.x;
    const int lp = bid & 7;           // level-pair 0..7  == XCD id
    const int chunk = bid >> 3;
    const long long base = (long long)chunk * 256;

    // cooperative coalesced load of this chunk's 768 x-floats
    for (int i = threadIdx.x; i < 768; i += 256) {
        long long gi = base * 3 + i;
        sx[i] = (gi < (long long)n_points * 3) ? x[gi] : 0.0f;
    }
    __syncthreads();

    const long long n = base + threadIdx.x;
    if (n >= n_points) return;

    // stride-3 LDS reads: gcd(3,32)=1 -> 2 lanes/bank max (free)
    const float x0 = sx[threadIdx.x * 3 + 0];
    const float x1 = sx[threadIdx.x * 3 + 1];
    const float x2 = sx[threadIdx.x * 3 + 2];

    const unsigned P1 = 2654435761u, P2 = 805459861u;
    const int l0 = lp * 2;
    const float rA = res.r[l0];       // kernarg, wave-uniform
    const float rB = res.r[l0 + 1];

    float4 v;
    {
        unsigned c0 = (unsigned)(int)floorf(x0 * rA);
        unsigned c1 = (unsigned)(int)floorf(x1 * rA);
        unsigned c2 = (unsigned)(int)floorf(x2 * rA);
        unsigned h = (c0 + c1 * P1 + c2 * P2) & HASH_MASK;
        const float2 f = ((const float2*)emb)[(size_t)l0 * HS + h];
        v.x = f.x; v.y = f.y;
    }
    {
        unsigned c0 = (unsigned)(int)floorf(x0 * rB);
        unsigned c1 = (unsigned)(int)floorf(x1 * rB);
        unsigned c2 = (unsigned)(int)floorf(x2 * rB);
        unsigned h = (c0 + c1 * P1 + c2 * P2) & HASH_MASK;
        const float2 f = ((const float2*)emb)[((size_t)l0 + 1) * HS + h];
        v.z = f.x; v.w = f.y;
    }
    ((float4*)out)[n * 8 + lp] = v;
}

extern "C" void kernel_launch(void* const* d_in, const int* in_sizes, int n_in,
                              void* d_out, int out_size, void* d_ws, size_t ws_size,
                              hipStream_t stream) {
    const float* x   = (const float*)d_in[0];
    const float* emb = (const float*)d_in[1];
    float* out = (float*)d_out;
    const int n = in_sizes[0] / 3;

    // Host-side RESOLUTIONS, identical arithmetic to the reference's Python
    // (libm pow + truncation), so the borderline level 15 (exact 2048.0)
    // truncates identically.
    ResArr res;
    const double b = pow(128.0, 1.0 / 15.0);
    for (int i = 0; i < NUM_LEVELS; i++) {
        res.r[i] = (float)(long long)(16.0 * pow(b, (double)i));
    }

    const int chunks = (n + 255) / 256;
    const int blocks = chunks * 8;    // bid = chunk*8 + lp
    HashEncoder_67963562492047_kernel<<<blocks, 256, 0, stream>>>(x, emb, out, res, n);
}

// Round 4
// 505.709 us; speedup vs baseline: 1.1630x; 1.1630x over previous
//
#include <hip/hip_runtime.h>
#include <math.h>

#define HASH_SIZE_LOG2 19
#define HASH_MASK ((1u << HASH_SIZE_LOG2) - 1u)
#define HS (1u << HASH_SIZE_LOG2)
#define NUM_LEVELS 16

typedef float f32x4 __attribute__((ext_vector_type(4)));

struct ResArr { float r[NUM_LEVELS]; };

// 256 threads = 32 points x 8 level-pairs, 4 points per thread (MLP).
// Thread t: lp = t&7 (levels 2lp, 2lp+1), pl = t>>3; handles points
// base + pl + 32j, j=0..3. All 8 gathers are issued before any use
// (separate index loop -> load loop), so 8 misses are in flight per thread.
// Store: f32x4 at out[n*32 + lp*4]; a wave's 64 stores cover 1KB contiguous.
// Output + x use non-temporal (evict-first) to keep L2 for embedding lines.
__global__ __launch_bounds__(256) void HashEncoder_67963562492047_kernel(
    const float* __restrict__ x,      // [N,3] f32
    const float* __restrict__ emb,    // [16][HS][2] f32
    float* __restrict__ out,          // [N,32] f32
    ResArr res, int n_points)
{
    __shared__ float sx[128 * 3];
    __shared__ float sres[NUM_LEVELS];

    const int t = threadIdx.x;
    const long long base = (long long)blockIdx.x * 128;

    if (t < NUM_LEVELS) sres[t] = res.r[t];
    for (int i = t; i < 384; i += 256) {
        long long gi = base * 3 + i;
        sx[i] = (gi < (long long)n_points * 3)
                    ? __builtin_nontemporal_load(&x[gi]) : 0.0f;
    }
    __syncthreads();

    const int lp = t & 7;
    const int pl = t >> 3;
    const int l0 = lp * 2;
    const float rA = sres[l0];
    const float rB = sres[l0 + 1];
    const unsigned P1 = 2654435761u, P2 = 805459861u;
    const float2* __restrict__ e2 = (const float2*)emb;

    unsigned ha[4], hb[4];
    #pragma unroll
    for (int j = 0; j < 4; j++) {
        const int pj = pl + j * 32;
        // OOB lanes read sx=0 -> h=0 -> safe dummy gather; store is guarded.
        const float x0 = sx[pj * 3 + 0];
        const float x1 = sx[pj * 3 + 1];
        const float x2 = sx[pj * 3 + 2];
        // exact f32 multiply+floor (matches jnp.floor(x*res) in f32);
        // int64 hash % 2^19 == uint32-wrapped sum & mask (2^19 | 2^32).
        unsigned a0 = (unsigned)(int)floorf(x0 * rA);
        unsigned a1 = (unsigned)(int)floorf(x1 * rA);
        unsigned a2 = (unsigned)(int)floorf(x2 * rA);
        unsigned b0 = (unsigned)(int)floorf(x0 * rB);
        unsigned b1 = (unsigned)(int)floorf(x1 * rB);
        unsigned b2 = (unsigned)(int)floorf(x2 * rB);
        ha[j] = (a0 + a1 * P1 + a2 * P2) & HASH_MASK;
        hb[j] = (b0 + b1 * P1 + b2 * P2) & HASH_MASK;
    }

    float2 fa[4], fb[4];
    #pragma unroll
    for (int j = 0; j < 4; j++) {
        fa[j] = e2[(size_t)l0 * HS + ha[j]];
        fb[j] = e2[((size_t)l0 + 1) * HS + hb[j]];
    }

    #pragma unroll
    for (int j = 0; j < 4; j++) {
        const long long n = base + pl + j * 32;
        if (n < n_points) {
            f32x4 v;
            v.x = fa[j].x; v.y = fa[j].y; v.z = fb[j].x; v.w = fb[j].y;
            __builtin_nontemporal_store(v, (f32x4*)out + (n * 8 + lp));
        }
    }
}

extern "C" void kernel_launch(void* const* d_in, const int* in_sizes, int n_in,
                              void* d_out, int out_size, void* d_ws, size_t ws_size,
                              hipStream_t stream) {
    const float* x   = (const float*)d_in[0];
    const float* emb = (const float*)d_in[1];
    float* out = (float*)d_out;
    const int n = in_sizes[0] / 3;

    // Host-side RESOLUTIONS, identical arithmetic to the reference's Python
    // (libm pow + truncation) so level 15 (exact 2048.0) truncates identically.
    ResArr res;
    const double b = pow(128.0, 1.0 / 15.0);
    for (int i = 0; i < NUM_LEVELS; i++) {
        res.r[i] = (float)(long long)(16.0 * pow(b, (double)i));
    }

    const int blocks = (n + 127) / 128;   // 128 points per block
    HashEncoder_67963562492047_kernel<<<blocks, 256, 0, stream>>>(x, emb, out, res, n);
}

// Round 5
// 351.719 us; speedup vs baseline: 1.6721x; 1.4378x over previous
//
#include <hip/hip_runtime.h>
#include <math.h>

#define HASH_SIZE_LOG2 19
#define HASH_MASK ((1u << HASH_SIZE_LOG2) - 1u)
#define HS (1u << HASH_SIZE_LOG2)
#define NUM_LEVELS 16
#define CHUNK 2048              // points per gather block

typedef float f32x2 __attribute__((ext_vector_type(2)));
typedef float f32x4 __attribute__((ext_vector_type(4)));

struct ResArr { float r[NUM_LEVELS]; };

// ---------------- Phase 1: level-pinned gather into ws[l][n] ----------------
// bid = seg*(8*chunks) + chunk*8 + (level%8), level = seg*8 + bid%8.
// XCD(bid) = bid%8 (round-robin dispatch) => level l runs ONLY on XCD l%8,
// and all seg-0 (levels 0-7) blocks dispatch before seg-1 (levels 8-15):
// each XCD streams through ONE 4MB table at a time -- exactly its L2 size ->
// near-full residency. x loads and ws stores are non-temporal so the
// streaming data doesn't evict the table. ws writes are wave-contiguous.
__global__ __launch_bounds__(256) void he_gather_kernel(
    const float* __restrict__ x,      // [N,3]
    const float* __restrict__ emb,    // [16][HS][2]
    f32x2* __restrict__ ws,           // [16][N]
    ResArr res, int n_points, int chunks)
{
    __shared__ float sx[CHUNK * 3];

    const int bid = blockIdx.x;
    const int seg = bid / (8 * chunks);
    const int r   = bid - seg * 8 * chunks;
    const int lvl = seg * 8 + (r & 7);
    const int chunk = r >> 3;
    const long long base = (long long)chunk * CHUNK;
    const int t = threadIdx.x;

    // cooperative nt load of this chunk's x (1536 float4 = 24KB)
    const f32x4* x4 = (const f32x4*)x;
    const long long nflt4 = ((long long)n_points * 3) / 4;
    for (int i = t; i < CHUNK * 3 / 4; i += 256) {
        long long gi = (long long)chunk * (CHUNK * 3 / 4) + i;
        f32x4 v = (gi < nflt4) ? __builtin_nontemporal_load(&x4[gi])
                               : (f32x4){0, 0, 0, 0};
        ((f32x4*)sx)[i] = v;
    }
    __syncthreads();

    const float rl = res.r[lvl];                         // wave-uniform
    const f32x2* __restrict__ table = (const f32x2*)emb + (size_t)lvl * HS;
    f32x2* __restrict__ wsl = ws + (size_t)lvl * n_points;
    const unsigned P1 = 2654435761u, P2 = 805459861u;

    unsigned h[8];
    #pragma unroll
    for (int j = 0; j < 8; j++) {
        const int p = t + j * 256;
        // exact f32 multiply+floor (matches jnp.floor(x*res) in f32);
        // int64 hash % 2^19 == uint32-wrapped sum & mask (2^19 | 2^32).
        unsigned c0 = (unsigned)(int)floorf(sx[p * 3 + 0] * rl);
        unsigned c1 = (unsigned)(int)floorf(sx[p * 3 + 1] * rl);
        unsigned c2 = (unsigned)(int)floorf(sx[p * 3 + 2] * rl);
        h[j] = (c0 + c1 * P1 + c2 * P2) & HASH_MASK;
    }
    f32x2 f[8];
    #pragma unroll
    for (int j = 0; j < 8; j++) f[j] = table[h[j]];      // temporal: L2-resident
    #pragma unroll
    for (int j = 0; j < 8; j++) {
        const long long n = base + t + j * 256;
        if (n < n_points) __builtin_nontemporal_store(f[j], &wsl[n]);
    }
}

// ---------------- Phase 2: streaming transpose ws[16][N] -> out[N][32] -----
__global__ __launch_bounds__(256) void he_transpose_kernel(
    const f32x2* __restrict__ ws, float* __restrict__ out, int n_points)
{
    __shared__ f32x2 sf[256 * 17];    // stride 17 float2: conflict-free writes
    const long long base = (long long)blockIdx.x * 256;
    const int t = threadIdx.x;
    const long long n = base + t;

    #pragma unroll
    for (int l = 0; l < NUM_LEVELS; l++) {
        f32x2 v = (n < n_points)
            ? __builtin_nontemporal_load(&ws[(size_t)l * n_points + n])
            : (f32x2){0, 0};
        sf[t * 17 + l] = v;
    }
    __syncthreads();

    #pragma unroll
    for (int j = 0; j < 8; j++) {
        const int i = t + j * 256;     // f32x4 index within block (0..2047)
        const int p = i >> 3;          // local point
        const int c2 = (i & 7) * 2;    // float2 offset in point row
        if (base + p < n_points) {
            f32x2 a = sf[p * 17 + c2];
            f32x2 b = sf[p * 17 + c2 + 1];
            f32x4 v = {a.x, a.y, b.x, b.y};
            __builtin_nontemporal_store(v, (f32x4*)out + (base * 8 + i));
        }
    }
}

// ---------------- Fallback (round-4 direct kernel) if ws too small ---------
__global__ __launch_bounds__(256) void he_direct_kernel(
    const float* __restrict__ x, const float* __restrict__ emb,
    float* __restrict__ out, ResArr res, int n_points)
{
    __shared__ float sx[128 * 3];
    __shared__ float sres[NUM_LEVELS];
    const int t = threadIdx.x;
    const long long base = (long long)blockIdx.x * 128;
    if (t < NUM_LEVELS) sres[t] = res.r[t];
    for (int i = t; i < 384; i += 256) {
        long long gi = base * 3 + i;
        sx[i] = (gi < (long long)n_points * 3)
                    ? __builtin_nontemporal_load(&x[gi]) : 0.0f;
    }
    __syncthreads();
    const int lp = t & 7, pl = t >> 3, l0 = lp * 2;
    const float rA = sres[l0], rB = sres[l0 + 1];
    const unsigned P1 = 2654435761u, P2 = 805459861u;
    const f32x2* __restrict__ e2 = (const f32x2*)emb;
    unsigned ha[4], hb[4];
    #pragma unroll
    for (int j = 0; j < 4; j++) {
        const int pj = pl + j * 32;
        const float x0 = sx[pj * 3], x1 = sx[pj * 3 + 1], x2 = sx[pj * 3 + 2];
        unsigned a0 = (unsigned)(int)floorf(x0 * rA);
        unsigned a1 = (unsigned)(int)floorf(x1 * rA);
        unsigned a2 = (unsigned)(int)floorf(x2 * rA);
        unsigned b0 = (unsigned)(int)floorf(x0 * rB);
        unsigned b1 = (unsigned)(int)floorf(x1 * rB);
        unsigned b2 = (unsigned)(int)floorf(x2 * rB);
        ha[j] = (a0 + a1 * P1 + a2 * P2) & HASH_MASK;
        hb[j] = (b0 + b1 * P1 + b2 * P2) & HASH_MASK;
    }
    f32x2 fa[4], fb[4];
    #pragma unroll
    for (int j = 0; j < 4; j++) {
        fa[j] = e2[(size_t)l0 * HS + ha[j]];
        fb[j] = e2[((size_t)l0 + 1) * HS + hb[j]];
    }
    #pragma unroll
    for (int j = 0; j < 4; j++) {
        const long long n = base + pl + j * 32;
        if (n < n_points) {
            f32x4 v = {fa[j].x, fa[j].y, fb[j].x, fb[j].y};
            __builtin_nontemporal_store(v, (f32x4*)out + (n * 8 + lp));
        }
    }
}

extern "C" void kernel_launch(void* const* d_in, const int* in_sizes, int n_in,
                              void* d_out, int out_size, void* d_ws, size_t ws_size,
                              hipStream_t stream) {
    const float* x   = (const float*)d_in[0];
    const float* emb = (const float*)d_in[1];
    float* out = (float*)d_out;
    const int n = in_sizes[0] / 3;

    // Host-side RESOLUTIONS, identical arithmetic to the reference's Python
    // (libm pow + truncation) so level 15 (exact 2048.0) truncates identically.
    ResArr res;
    const double b = pow(128.0, 1.0 / 15.0);
    for (int i = 0; i < NUM_LEVELS; i++) {
        res.r[i] = (float)(long long)(16.0 * pow(b, (double)i));
    }

    const size_t ws_need = (size_t)NUM_LEVELS * (size_t)n * sizeof(f32x2);
    if (ws_size >= ws_need) {
        const int chunks = (n + CHUNK - 1) / CHUNK;
        he_gather_kernel<<<2 * 8 * chunks, 256, 0, stream>>>(
            x, emb, (f32x2*)d_ws, res, n, chunks);
        he_transpose_kernel<<<(n + 255) / 256, 256, 0, stream>>>(
            (const f32x2*)d_ws, out, n);
    } else {
        he_direct_kernel<<<(n + 127) / 128, 256, 0, stream>>>(x, emb, out, res, n);
    }
}

// Round 6
// 342.357 us; speedup vs baseline: 1.7178x; 1.0273x over previous
//
#include <hip/hip_runtime.h>
#include <math.h>

#define HASH_SIZE_LOG2 19
#define HASH_MASK ((1u << HASH_SIZE_LOG2) - 1u)
#define HS (1u << HASH_SIZE_LOG2)
#define NUM_LEVELS 16
#define CHUNK 2048              // points per gather block

typedef float f32x2 __attribute__((ext_vector_type(2)));
typedef float f32x4 __attribute__((ext_vector_type(4)));

struct ResArr { float r[NUM_LEVELS]; };

// Static schedule: 16 levels x 8 eighths = 128 tasks, assigned to 8 XCDs x
// 16 slots. "Full" levels (5..15, table footprint ~4MB) give 88 tasks -> 11
// per XCD; "small" levels (0..4, footprint <= 1.6MB) give 40 -> 5 per XCD.
// Every XCD gets exactly 11 full-eighths + 5 small-eighths: balanced under
// any cost ratio. Tasks of the same level are adjacent in slot order, so an
// XCD streams through ~2-3 distinct full tables sequentially (L2-resident).
struct Sched {
    unsigned char lvl[128];   // [xcd][slot]
    unsigned char oct[128];   // eighth index 0..7
    ResArr res;
};

// ---------------- Phase 1: balanced level-pinned gather into ws[l][n] ------
// bid = (slot*ochunks + c)*8 + xcd ; XCD(bid) = bid%8 (round-robin dispatch)
// -> task (lvl,oct) runs entirely on its assigned XCD, slots in order.
__global__ __launch_bounds__(256) void he_gather_kernel(
    const float* __restrict__ x,      // [N,3]
    const float* __restrict__ emb,    // [16][HS][2]
    f32x2* __restrict__ ws,           // [16][N]
    Sched sc, int n_points, int ochunks, int chunks)
{
    __shared__ float sx[CHUNK * 3];

    const int bid = blockIdx.x;
    const int xcd = bid & 7;
    const int r = bid >> 3;
    const int slot = r / ochunks;
    const int c = r - slot * ochunks;
    const int lvl = sc.lvl[xcd * 16 + slot];
    const int chunk = (int)sc.oct[xcd * 16 + slot] * ochunks + c;
    if (chunk >= chunks) return;

    const long long base = (long long)chunk * CHUNK;
    const int t = threadIdx.x;

    // cooperative nt load of this chunk's x (1536 f32x4 = 24KB)
    const f32x4* x4 = (const f32x4*)x;
    const long long nflt4 = ((long long)n_points * 3) / 4;
    for (int i = t; i < CHUNK * 3 / 4; i += 256) {
        long long gi = (long long)chunk * (CHUNK * 3 / 4) + i;
        f32x4 v = (gi < nflt4) ? __builtin_nontemporal_load(&x4[gi])
                               : (f32x4){0, 0, 0, 0};
        ((f32x4*)sx)[i] = v;
    }
    __syncthreads();

    const float rl = sc.res.r[lvl];                      // wave-uniform
    const f32x2* __restrict__ table = (const f32x2*)emb + (size_t)lvl * HS;
    f32x2* __restrict__ wsl = ws + (size_t)lvl * n_points;
    const unsigned P1 = 2654435761u, P2 = 805459861u;

    unsigned h[8];
    #pragma unroll
    for (int j = 0; j < 8; j++) {
        const int p = t + j * 256;
        // exact f32 multiply+floor (matches jnp.floor(x*res) in f32);
        // int64 hash % 2^19 == uint32-wrapped sum & mask (2^19 | 2^32).
        unsigned c0 = (unsigned)(int)floorf(sx[p * 3 + 0] * rl);
        unsigned c1 = (unsigned)(int)floorf(sx[p * 3 + 1] * rl);
        unsigned c2 = (unsigned)(int)floorf(sx[p * 3 + 2] * rl);
        h[j] = (c0 + c1 * P1 + c2 * P2) & HASH_MASK;
    }
    f32x2 f[8];
    #pragma unroll
    for (int j = 0; j < 8; j++) f[j] = table[h[j]];      // temporal: L2-resident
    #pragma unroll
    for (int j = 0; j < 8; j++) {
        const long long n = base + t + j * 256;
        if (n < n_points) __builtin_nontemporal_store(f[j], &wsl[n]);
    }
}

// ---------------- Phase 2: streaming transpose ws[16][N] -> out[N][32] -----
__global__ __launch_bounds__(256) void he_transpose_kernel(
    const f32x2* __restrict__ ws, float* __restrict__ out, int n_points)
{
    __shared__ f32x2 sf[256 * 17];    // stride 17 float2: conflict-free writes
    const long long base = (long long)blockIdx.x * 256;
    const int t = threadIdx.x;
    const long long n = base + t;

    #pragma unroll
    for (int l = 0; l < NUM_LEVELS; l++) {
        f32x2 v = (n < n_points)
            ? __builtin_nontemporal_load(&ws[(size_t)l * n_points + n])
            : (f32x2){0, 0};
        sf[t * 17 + l] = v;
    }
    __syncthreads();

    #pragma unroll
    for (int j = 0; j < 8; j++) {
        const int i = t + j * 256;     // f32x4 index within block (0..2047)
        const int p = i >> 3;          // local point
        const int c2 = (i & 7) * 2;    // float2 offset in point row
        if (base + p < n_points) {
            f32x2 a = sf[p * 17 + c2];
            f32x2 b = sf[p * 17 + c2 + 1];
            f32x4 v = {a.x, a.y, b.x, b.y};
            __builtin_nontemporal_store(v, (f32x4*)out + (base * 8 + i));
        }
    }
}

// ---------------- Fallback (direct) if ws too small ------------------------
__global__ __launch_bounds__(256) void he_direct_kernel(
    const float* __restrict__ x, const float* __restrict__ emb,
    float* __restrict__ out, ResArr res, int n_points)
{
    __shared__ float sx[128 * 3];
    __shared__ float sres[NUM_LEVELS];
    const int t = threadIdx.x;
    const long long base = (long long)blockIdx.x * 128;
    if (t < NUM_LEVELS) sres[t] = res.r[t];
    for (int i = t; i < 384; i += 256) {
        long long gi = base * 3 + i;
        sx[i] = (gi < (long long)n_points * 3)
                    ? __builtin_nontemporal_load(&x[gi]) : 0.0f;
    }
    __syncthreads();
    const int lp = t & 7, pl = t >> 3, l0 = lp * 2;
    const float rA = sres[l0], rB = sres[l0 + 1];
    const unsigned P1 = 2654435761u, P2 = 805459861u;
    const f32x2* __restrict__ e2 = (const f32x2*)emb;
    unsigned ha[4], hb[4];
    #pragma unroll
    for (int j = 0; j < 4; j++) {
        const int pj = pl + j * 32;
        const float x0 = sx[pj * 3], x1 = sx[pj * 3 + 1], x2 = sx[pj * 3 + 2];
        unsigned a0 = (unsigned)(int)floorf(x0 * rA);
        unsigned a1 = (unsigned)(int)floorf(x1 * rA);
        unsigned a2 = (unsigned)(int)floorf(x2 * rA);
        unsigned b0 = (unsigned)(int)floorf(x0 * rB);
        unsigned b1 = (unsigned)(int)floorf(x1 * rB);
        unsigned b2 = (unsigned)(int)floorf(x2 * rB);
        ha[j] = (a0 + a1 * P1 + a2 * P2) & HASH_MASK;
        hb[j] = (b0 + b1 * P1 + b2 * P2) & HASH_MASK;
    }
    f32x2 fa[4], fb[4];
    #pragma unroll
    for (int j = 0; j < 4; j++) {
        fa[j] = e2[(size_t)l0 * HS + ha[j]];
        fb[j] = e2[((size_t)l0 + 1) * HS + hb[j]];
    }
    #pragma unroll
    for (int j = 0; j < 4; j++) {
        const long long n = base + pl + j * 32;
        if (n < n_points) {
            f32x4 v = {fa[j].x, fa[j].y, fb[j].x, fb[j].y};
            __builtin_nontemporal_store(v, (f32x4*)out + (n * 8 + lp));
        }
    }
}

extern "C" void kernel_launch(void* const* d_in, const int* in_sizes, int n_in,
                              void* d_out, int out_size, void* d_ws, size_t ws_size,
                              hipStream_t stream) {
    const float* x   = (const float*)d_in[0];
    const float* emb = (const float*)d_in[1];
    float* out = (float*)d_out;
    const int n = in_sizes[0] / 3;

    // Host-side RESOLUTIONS, identical arithmetic to the reference's Python
    // (libm pow + truncation) so level 15 (exact 2048.0) truncates identically.
    ResArr res;
    const double b = pow(128.0, 1.0 / 15.0);
    for (int i = 0; i < NUM_LEVELS; i++) {
        res.r[i] = (float)(long long)(16.0 * pow(b, (double)i));
    }

    const size_t ws_need = (size_t)NUM_LEVELS * (size_t)n * sizeof(f32x2);
    if (ws_size >= ws_need) {
        Sched sc;
        sc.res = res;
        // full levels 5..15: 88 eighth-tasks -> 11 per XCD, slots 0..10,
        // same-level tasks adjacent (each XCD spans <=3 distinct tables).
        for (int q = 0; q < 88; q++) {
            int xcd = q / 11, slot = q % 11;
            sc.lvl[xcd * 16 + slot] = (unsigned char)(5 + q / 8);
            sc.oct[xcd * 16 + slot] = (unsigned char)(q % 8);
        }
        // small levels 0..4: 40 eighth-tasks -> 5 per XCD, slots 11..15.
        for (int s = 0; s < 40; s++) {
            int xcd = s / 5, slot = 11 + s % 5;
            sc.lvl[xcd * 16 + slot] = (unsigned char)(s / 8);
            sc.oct[xcd * 16 + slot] = (unsigned char)(s % 8);
        }
        const int chunks = (n + CHUNK - 1) / CHUNK;
        const int ochunks = (chunks + 7) / 8;
        he_gather_kernel<<<8 * 16 * ochunks, 256, 0, stream>>>(
            x, emb, (f32x2*)d_ws, sc, n, ochunks, chunks);
        he_transpose_kernel<<<(n + 255) / 256, 256, 0, stream>>>(
            (const f32x2*)d_ws, out, n);
    } else {
        he_direct_kernel<<<(n + 127) / 128, 256, 0, stream>>>(x, emb, out, res, n);
    }
}